// Round 1
// 664.808 us; speedup vs baseline: 1.1773x; 1.1773x over previous
//
#include <hip/hip_runtime.h>
#include <hip/hip_bf16.h>
#include <cstdint>

#define NP_PEP 50000
#define NP_PROT 8000
#define NE 1600000
#define NEL 200000
#define F_IN 1280
#define HDIM 128

// CSR binning constants
#define CHUNK 4096
#define NBLK 391            // ceil(NE/CHUNK)
#define NBQ 500             // prot buckets (16 nodes each, d>>4)
#define SHQ 4
#define NPBQ 16
#define NBP 391             // pep buckets (128 nodes each, s>>7)
#define SHP 7
#define NPBP 128

// grid split constants for merged kernels
#define PROJ_BLK_PEP 391    // ceil(50000/128)
#define PROJ_BLK_PROT 63    // ceil(8000/128)
#define AGG_BLK_PROT 2000   // ceil(8000/4)
#define AGG_BLK_PEP 12500   // ceil(50000/4)

typedef __attribute__((ext_vector_type(8))) short bfrag;   // 8 bf16 (4 VGPRs)
typedef __attribute__((ext_vector_type(4))) short bhalf4;  // 4 bf16 (8 B)
typedef __attribute__((ext_vector_type(4))) float f32x4;

__device__ __forceinline__ ushort f2bf(float x) {          // native RNE fp32->bf16
    __hip_bfloat16 h = __float2bfloat16(x);
    ushort u;
    __builtin_memcpy(&u, &h, 2);
    return u;
}
__device__ inline void unpack2(uint u, float& lo, float& hi) {
    union { uint u; float f; } a, b;
    a.u = u << 16; b.u = u & 0xffff0000u;
    lo = a.f; hi = b.f;
}
__device__ inline uint pack2(float a, float b) {
    return (uint)f2bf(a) | ((uint)f2bf(b) << 16);
}

// async 16B global -> LDS (wave-uniform base + lane*16; our layouts are linear in tid)
__device__ __forceinline__ void cp16_g2l(const void* g, void* l) {
    __builtin_amdgcn_global_load_lds(
        (const __attribute__((address_space(1))) void*)g,
        (__attribute__((address_space(3))) void*)l, 16, 0, 0);
}

// ---------------- CSR build (bucket-local, no per-node global atomics) ----------------

__global__ __launch_bounds__(512) void bin_count(const int* __restrict__ esrc,
                                                 const int* __restrict__ edst,
                                                 int* __restrict__ Gq,   // [NBQ][NBLK]
                                                 int* __restrict__ Gp) { // [NBP][NBLK]
    __shared__ int hq[NBQ];
    __shared__ int hp[NBP];
    int b = blockIdx.x, t = threadIdx.x;
    if (t < NBQ) hq[t] = 0;
    if (t < NBP) hp[t] = 0;
    __syncthreads();
    int e0 = b * CHUNK, cnt = min(CHUNK, NE - e0);
#pragma unroll
    for (int r = 0; r < 8; ++r) {
        int i = t + r * 512;
        if (i < cnt) {
            atomicAdd(&hq[edst[e0 + i] >> SHQ], 1);
            atomicAdd(&hp[esrc[e0 + i] >> SHP], 1);
        }
    }
    __syncthreads();
    if (t < NBQ) Gq[t * NBLK + b] = hq[t];
    if (t < NBP) Gp[t * NBLK + b] = hp[t];
}

__global__ __launch_bounds__(512) void rel_offsets(const int* __restrict__ Gq,
                                                   int* __restrict__ Oq, int* __restrict__ Tq,
                                                   const int* __restrict__ Gp,
                                                   int* __restrict__ Op, int* __restrict__ Tp) {
    const int* G; int* O; int* T; int j;
    if (blockIdx.x < NBQ) { G = Gq; O = Oq; T = Tq; j = blockIdx.x; }
    else                  { G = Gp; O = Op; T = Tp; j = blockIdx.x - NBQ; }
    __shared__ int sh[512];
    int t = threadIdx.x;
    int v = (t < NBLK) ? G[j * NBLK + t] : 0;
    sh[t] = v;
    __syncthreads();
    for (int off = 1; off < 512; off <<= 1) {
        int a = sh[t];
        int c = (t >= off) ? sh[t - off] : 0;
        __syncthreads();
        sh[t] = a + c;
        __syncthreads();
    }
    if (t < NBLK) O[j * NBLK + t] = sh[t] - v;
    if (t == 511) T[j] = sh[511];
}

__global__ __launch_bounds__(512) void base_scan(const int* __restrict__ Tq, int* __restrict__ Bq,
                                                 const int* __restrict__ Tp, int* __restrict__ Bp) {
    __shared__ int sh[512];
    int t = threadIdx.x;
    int v = (t < NBQ) ? Tq[t] : 0;
    sh[t] = v;
    __syncthreads();
    for (int off = 1; off < 512; off <<= 1) {
        int a = sh[t];
        int c = (t >= off) ? sh[t - off] : 0;
        __syncthreads();
        sh[t] = a + c;
        __syncthreads();
    }
    if (t < NBQ) Bq[t] = sh[t] - v;
    if (t == 0) Bq[NBQ] = NE;
    __syncthreads();
    int v2 = (t < NBP) ? Tp[t] : 0;
    sh[t] = v2;
    __syncthreads();
    for (int off = 1; off < 512; off <<= 1) {
        int a = sh[t];
        int c = (t >= off) ? sh[t - off] : 0;
        __syncthreads();
        sh[t] = a + c;
        __syncthreads();
    }
    if (t < NBP) Bp[t] = sh[t] - v2;
    if (t == 0) Bp[NBP] = NE;
}

__global__ __launch_bounds__(512) void bin_scatter2(const int* __restrict__ esrc,
                                                    const int* __restrict__ edst,
                                                    const int* __restrict__ Oq,
                                                    const int* __restrict__ Bq,
                                                    const int* __restrict__ Op,
                                                    const int* __restrict__ Bp,
                                                    uint* __restrict__ stagQ,
                                                    uint* __restrict__ stagP) {
    __shared__ int hist[512];
    __shared__ int start[512];
    __shared__ uint sorted[CHUNK];
    int b = blockIdx.x, t = threadIdx.x;
    int e0 = b * CHUNK, cnt = min(CHUNK, NE - e0);
    uint pk[8];
    bool val[8];
#pragma unroll
    for (int r = 0; r < 8; ++r) {
        int i = t + r * 512;
        val[r] = (i < cnt);
        if (val[r]) {
            int s = esrc[e0 + i], d = edst[e0 + i];
            pk[r] = ((uint)s << 13) | (uint)d;
        }
    }
    for (int dir = 0; dir < 2; ++dir) {
        const int* O = dir ? Op : Oq;
        const int* B = dir ? Bp : Bq;
        uint* stg = dir ? stagP : stagQ;
        int shf = dir ? SHP : SHQ;
        hist[t] = 0;
        __syncthreads();
        int bk[8];
#pragma unroll
        for (int r = 0; r < 8; ++r) {
            bk[r] = -1;
            if (val[r]) {
                int key = dir ? (int)(pk[r] >> 13) : (int)(pk[r] & 8191u);
                bk[r] = key >> shf;
                atomicAdd(&hist[bk[r]], 1);
            }
        }
        __syncthreads();
        int ownv = hist[t];
        start[t] = ownv;
        __syncthreads();
        for (int off = 1; off < 512; off <<= 1) {
            int a = start[t];
            int c = (t >= off) ? start[t - off] : 0;
            __syncthreads();
            start[t] = a + c;
            __syncthreads();
        }
        int excl = start[t] - ownv;
        start[t] = excl;
        hist[t] = excl;
        __syncthreads();
#pragma unroll
        for (int r = 0; r < 8; ++r)
            if (bk[r] >= 0) {
                int rank = atomicAdd(&hist[bk[r]], 1);
                sorted[rank] = pk[r];
            }
        __syncthreads();
#pragma unroll
        for (int r = 0; r < 8; ++r) {
            int i = t + r * 512;
            if (i < cnt) {
                uint v = sorted[i];
                int key = dir ? (int)(v >> 13) : (int)(v & 8191u);
                int bb = key >> shf;
                stg[B[bb] + O[bb * NBLK + b] + (i - start[bb])] = v;
            }
        }
        __syncthreads();
    }
}

__global__ __launch_bounds__(256) void finalize_csr(const uint* __restrict__ stagQ,
                                                    const int* __restrict__ Bq,
                                                    int* __restrict__ rowptr_prot,
                                                    int* __restrict__ col_prot,
                                                    const uint* __restrict__ stagP,
                                                    const int* __restrict__ Bp,
                                                    int* __restrict__ rowptr_pep,
                                                    int* __restrict__ col_pep) {
    __shared__ int cnts[128];
    __shared__ int sc[128];
    __shared__ int cur[128];
    const uint* stg; const int* B; int* rowptr; int* col;
    int n, npb, j, use_dst;
    if (blockIdx.x < NBQ) {
        stg = stagQ; B = Bq; rowptr = rowptr_prot; col = col_prot;
        n = NP_PROT; npb = NPBQ; j = blockIdx.x; use_dst = 1;
    } else {
        stg = stagP; B = Bp; rowptr = rowptr_pep; col = col_pep;
        n = NP_PEP; npb = NPBP; j = blockIdx.x - NBQ; use_dst = 0;
    }
    int t = threadIdx.x;
    int first = j * npb;
    int nn = min(npb, n - first);
    if (t < 128) cnts[t] = 0;
    __syncthreads();
    int s0 = B[j], s1 = B[j + 1];
    for (int i = s0 + t; i < s1; i += 256) {
        uint v = stg[i];
        int key = use_dst ? (int)(v & 8191u) : (int)(v >> 13);
        atomicAdd(&cnts[key - first], 1);
    }
    __syncthreads();
    int v = 0;
    if (t < 128) { v = cnts[t]; sc[t] = v; }
    __syncthreads();
    for (int off = 1; off < 128; off <<= 1) {
        int a = 0, c = 0;
        if (t < 128) { a = sc[t]; c = (t >= off) ? sc[t - off] : 0; }
        __syncthreads();
        if (t < 128) sc[t] = a + c;
        __syncthreads();
    }
    if (t < nn) {
        int excl = sc[t] - v;
        rowptr[first + t] = s0 + excl;
        cur[t] = s0 + excl;
    }
    if (t == 0 && j == 0) rowptr[n] = NE;
    __syncthreads();
    for (int i = s0 + t; i < s1; i += 256) {
        uint v2 = stg[i];
        int key, pay;
        if (use_dst) { key = (int)(v2 & 8191u); pay = (int)(v2 >> 13); }
        else         { key = (int)(v2 >> 13);   pay = (int)(v2 & 8191u); }
        int pos = atomicAdd(&cur[key - first], 1);
        col[pos] = pay;
    }
}

// ---------------- weight pre-bake: fp32 W -> bf16 pre-swizzled B-fragment images -------
// Image per 32-row k-tile: 4096 ushorts; elem [idx*8+j] = W[kt*32 + h*8 + j][n]
// with n = ((idx>>6)<<4)|(idx&15), h = (idx>>4)&3  (idx = frag index 0..511).
// This is byte-identical to the LDS content the GEMM MFMA loop expects, so staging
// becomes two linear global_load_lds per thread.

#define WST_TILE 4096

__global__ __launch_bounds__(256) void wprep(const float* __restrict__ Wp,
                                             const float* __restrict__ Wq,
                                             const float* __restrict__ m0,
                                             const float* __restrict__ m1,
                                             const float* __restrict__ m2,
                                             const float* __restrict__ m3,
                                             const float* __restrict__ m4,
                                             const float* __restrict__ m5,
                                             const float* __restrict__ m6,
                                             const float* __restrict__ m7,
                                             ushort* __restrict__ out) {
    int b = blockIdx.x;
    const float* W; int kt; size_t base;
    if (b < 40)      { W = Wp; kt = b;       base = 0; }
    else if (b < 80) { W = Wq; kt = b - 40;  base = (size_t)40 * WST_TILE; }
    else {
        int mm = (b - 80) >> 2; kt = (b - 80) & 3;
        switch (mm) {
            case 0: W = m0; break; case 1: W = m1; break;
            case 2: W = m2; break; case 3: W = m3; break;
            case 4: W = m4; break; case 5: W = m5; break;
            case 6: W = m6; break; default: W = m7; break;
        }
        base = (size_t)(80 + 4 * mm) * WST_TILE;
    }
    int t = threadIdx.x;
#pragma unroll
    for (int r = 0; r < 2; ++r) {
        int idx = t + r * 256;
        int n = ((idx >> 6) << 4) | (idx & 15);
        int h = (idx >> 4) & 3;
        const float* wp = W + (size_t)(kt * 32 + h * 8) * HDIM + n;
        bfrag p;
#pragma unroll
        for (int j = 0; j < 8; ++j) p[j] = (short)f2bf(wp[(size_t)j * HDIM]);
        *(bfrag*)&out[base + (size_t)kt * WST_TILE + (size_t)idx * 8] = p;
    }
}

// -------- merged projection: C[M,128](bf16) = A[M,1280](f32) @ W + b, 2 jobs --------
__global__ __launch_bounds__(256) void gemm_proj2(const float* __restrict__ Aa,
                                                  const ushort* __restrict__ Wsta,
                                                  const float* __restrict__ ba,
                                                  ushort* __restrict__ Ca, int Ma, int nblk_a,
                                                  const float* __restrict__ Ab,
                                                  const ushort* __restrict__ Wstb,
                                                  const float* __restrict__ bb,
                                                  ushort* __restrict__ Cb, int Mb) {
    __shared__ ushort Alds[4096];
    __shared__ ushort Blds[4096];
    __shared__ ushort Clds[128 * 136];
    const float* A; const ushort* Wst; const float* bias; ushort* Cg; int M, blk;
    if ((int)blockIdx.x < nblk_a) { A = Aa; Wst = Wsta; bias = ba; Cg = Ca; M = Ma; blk = blockIdx.x; }
    else                          { A = Ab; Wst = Wstb; bias = bb; Cg = Cb; M = Mb; blk = blockIdx.x - nblk_a; }
    int tid = threadIdx.x;
    int lane = tid & 63, w = tid >> 6, wm = w >> 1, wn = w & 1;
    int r0 = blk * 128;

    f32x4 acc[4][4];
#pragma unroll
    for (int i = 0; i < 4; ++i)
#pragma unroll
        for (int j = 0; j < 4; ++j) acc[i][j] = (f32x4){0.f, 0.f, 0.f, 0.f};

    for (int kt = 0; kt < F_IN / 32; ++kt) {
        int k0 = kt * 32;
        // W tile: async, pre-swizzled global image -> linear LDS
        const ushort* wsrc = Wst + (size_t)kt * WST_TILE;
        cp16_g2l(wsrc + (size_t)tid * 8, &Blds[(size_t)tid * 8]);
        cp16_g2l(wsrc + 2048 + (size_t)tid * 8, &Blds[2048 + (size_t)tid * 8]);
        // A tile: reg-stage fp32 -> bf16 (native pk cvt)
#pragma unroll
        for (int i = 0; i < 4; ++i) {
            int idx = tid + 256 * i;
            int row = idx >> 3, q = idx & 7;
            int gr = min(r0 + row, M - 1);
            float4 v = *(const float4*)(A + (size_t)gr * F_IN + k0 + q * 4);
            bhalf4 p;
            p.x = (short)f2bf(v.x); p.y = (short)f2bf(v.y);
            p.z = (short)f2bf(v.z); p.w = (short)f2bf(v.w);
            int off = ((row >> 4) * 64 + ((q >> 1) << 4) + (row & 15)) * 8 + (q & 1) * 4;
            *(bhalf4*)&Alds[off] = p;
        }
        __syncthreads();
        const bfrag* Af = (const bfrag*)Alds;
        const bfrag* Bf = (const bfrag*)Blds;
        bfrag af[4], bf_[4];
#pragma unroll
        for (int i = 0; i < 4; ++i) af[i] = Af[(wm * 4 + i) * 64 + lane];
#pragma unroll
        for (int j = 0; j < 4; ++j) bf_[j] = Bf[(wn * 4 + j) * 64 + lane];
#pragma unroll
        for (int i = 0; i < 4; ++i)
#pragma unroll
            for (int j = 0; j < 4; ++j)
                acc[i][j] = __builtin_amdgcn_mfma_f32_16x16x32_bf16(af[i], bf_[j], acc[i][j], 0, 0, 0);
        __syncthreads();
    }
#pragma unroll
    for (int j = 0; j < 4; ++j) {
        int colL = wn * 64 + j * 16 + (lane & 15);
        float bcol = bias[colL];
#pragma unroll
        for (int i = 0; i < 4; ++i) {
            int rbase = wm * 64 + i * 16 + ((lane >> 4) << 2);
            f32x4 v = acc[i][j];
            Clds[(rbase + 0) * 136 + colL] = f2bf(v.x + bcol);
            Clds[(rbase + 1) * 136 + colL] = f2bf(v.y + bcol);
            Clds[(rbase + 2) * 136 + colL] = f2bf(v.z + bcol);
            Clds[(rbase + 3) * 136 + colL] = f2bf(v.w + bcol);
        }
    }
    __syncthreads();
#pragma unroll
    for (int c = 0; c < 8; ++c) {
        int cidx = c * 256 + tid;
        int row = cidx >> 4, h = cidx & 15;
        int gr = r0 + row;
        if (gr < M)
            *(bfrag*)(Cg + (size_t)gr * HDIM + h * 8) = *(const bfrag*)&Clds[row * 136 + h * 8];
    }
}

// ---- merged fused linear (bf16): C = A1@W1 + A2@W2 + b (+relu), 2 jobs. C may alias A1.
// All staging (A and pre-baked W) is async global_load_lds.
__global__ __launch_bounds__(256) void lin2f(const ushort* A1a, const ushort* W1a,
                                             const ushort* A2a, const ushort* W2a,
                                             const float* __restrict__ ba,
                                             ushort* Ca, int Ma, int nblk_a,
                                             const ushort* A1b, const ushort* W1b,
                                             const ushort* A2b, const ushort* W2b,
                                             const float* __restrict__ bb,
                                             ushort* Cb, int Mb, int do_relu) {
    __shared__ ushort Alds[4096];
    __shared__ ushort Blds[4096];
    __shared__ ushort Clds[128 * 136];
    const ushort *A1, *A2, *W1, *W2; const float* bias; ushort* C; int M, blk;
    if ((int)blockIdx.x < nblk_a) {
        A1 = A1a; W1 = W1a; A2 = A2a; W2 = W2a; bias = ba; C = Ca; M = Ma; blk = blockIdx.x;
    } else {
        A1 = A1b; W1 = W1b; A2 = A2b; W2 = W2b; bias = bb; C = Cb; M = Mb; blk = blockIdx.x - nblk_a;
    }
    int tid = threadIdx.x;
    int lane = tid & 63, w = tid >> 6, wm = w >> 1, wn = w & 1;
    int r0 = blk * 128;

    // frag-index decomposition for async A staging (linear LDS image)
    int arow = ((tid >> 6) << 4) | (tid & 15);
    int ah = (tid >> 4) & 3;
    int gr1 = min(r0 + arow, M - 1);
    int gr2 = min(r0 + arow + 64, M - 1);

    f32x4 acc[4][4];
#pragma unroll
    for (int i = 0; i < 4; ++i)
#pragma unroll
        for (int j = 0; j < 4; ++j) acc[i][j] = (f32x4){0.f, 0.f, 0.f, 0.f};

    for (int kt = 0; kt < 8; ++kt) {
        const ushort* A = (kt < 4) ? A1 : A2;
        const ushort* Wt = (kt < 4) ? W1 : W2;
        int k0 = (kt & 3) * 32;
        cp16_g2l(A + (size_t)gr1 * HDIM + k0 + ah * 8, &Alds[(size_t)tid * 8]);
        cp16_g2l(A + (size_t)gr2 * HDIM + k0 + ah * 8, &Alds[(size_t)(tid + 256) * 8]);
        const ushort* wsrc = Wt + (size_t)(kt & 3) * WST_TILE;
        cp16_g2l(wsrc + (size_t)tid * 8, &Blds[(size_t)tid * 8]);
        cp16_g2l(wsrc + 2048 + (size_t)tid * 8, &Blds[2048 + (size_t)tid * 8]);
        __syncthreads();
        const bfrag* Af = (const bfrag*)Alds;
        const bfrag* Bf = (const bfrag*)Blds;
        bfrag af[4], bf_[4];
#pragma unroll
        for (int i = 0; i < 4; ++i) af[i] = Af[(wm * 4 + i) * 64 + lane];
#pragma unroll
        for (int j = 0; j < 4; ++j) bf_[j] = Bf[(wn * 4 + j) * 64 + lane];
#pragma unroll
        for (int i = 0; i < 4; ++i)
#pragma unroll
            for (int j = 0; j < 4; ++j)
                acc[i][j] = __builtin_amdgcn_mfma_f32_16x16x32_bf16(af[i], bf_[j], acc[i][j], 0, 0, 0);
        __syncthreads();
    }
#pragma unroll
    for (int j = 0; j < 4; ++j) {
        int colL = wn * 64 + j * 16 + (lane & 15);
        float bcol = bias[colL];
#pragma unroll
        for (int i = 0; i < 4; ++i) {
            int rbase = wm * 64 + i * 16 + ((lane >> 4) << 2);
            f32x4 v = acc[i][j];
            float o0 = v.x + bcol, o1 = v.y + bcol, o2 = v.z + bcol, o3 = v.w + bcol;
            if (do_relu) {
                o0 = fmaxf(o0, 0.f); o1 = fmaxf(o1, 0.f);
                o2 = fmaxf(o2, 0.f); o3 = fmaxf(o3, 0.f);
            }
            Clds[(rbase + 0) * 136 + colL] = f2bf(o0);
            Clds[(rbase + 1) * 136 + colL] = f2bf(o1);
            Clds[(rbase + 2) * 136 + colL] = f2bf(o2);
            Clds[(rbase + 3) * 136 + colL] = f2bf(o3);
        }
    }
    __syncthreads();
#pragma unroll
    for (int c = 0; c < 8; ++c) {
        int cidx = c * 256 + tid;
        int row = cidx >> 4, h = cidx & 15;
        int gr = r0 + row;
        if (gr < M)
            *(bfrag*)(C + (size_t)gr * HDIM + h * 8) = *(const bfrag*)&Clds[row * 136 + h * 8];
    }
}

// ------- merged mean aggregation (bf16 tables): one wave/node, 2-deep pipelined -------
__global__ __launch_bounds__(256) void aggr2(const ushort* __restrict__ Ha,
                                             const int* __restrict__ rpa,
                                             const int* __restrict__ cola,
                                             ushort* __restrict__ Oa, int Na, int nblk_a,
                                             const ushort* __restrict__ Hb,
                                             const int* __restrict__ rpb,
                                             const int* __restrict__ colb,
                                             ushort* __restrict__ Ob, int Nb) {
    const ushort* H; const int* rp; const int* col; ushort* O; int N, blk;
    if ((int)blockIdx.x < nblk_a) { H = Ha; rp = rpa; col = cola; O = Oa; N = Na; blk = blockIdx.x; }
    else                          { H = Hb; rp = rpb; col = colb; O = Ob; N = Nb; blk = blockIdx.x - nblk_a; }
    int node = blk * 4 + (threadIdx.x >> 6);
    if (node >= N) return;
    int lane = threadIdx.x & 63;
    int sub = lane >> 4;
    int ch = lane & 15;
    int beg = rp[node], end = rp[node + 1];
    int deg = end - beg;
    float a0 = 0, a1 = 0, a2 = 0, a3 = 0, a4 = 0, a5 = 0, a6 = 0, a7 = 0;
    int j = beg + sub;
    for (; j + 4 < end; j += 8) {
        int i0 = col[j], i1 = col[j + 4];
        uint4 u0 = *(const uint4*)(H + (size_t)i0 * HDIM + ch * 8);
        uint4 u1 = *(const uint4*)(H + (size_t)i1 * HDIM + ch * 8);
        float lo, hi;
        unpack2(u0.x, lo, hi); a0 += lo; a1 += hi;
        unpack2(u0.y, lo, hi); a2 += lo; a3 += hi;
        unpack2(u0.z, lo, hi); a4 += lo; a5 += hi;
        unpack2(u0.w, lo, hi); a6 += lo; a7 += hi;
        unpack2(u1.x, lo, hi); a0 += lo; a1 += hi;
        unpack2(u1.y, lo, hi); a2 += lo; a3 += hi;
        unpack2(u1.z, lo, hi); a4 += lo; a5 += hi;
        unpack2(u1.w, lo, hi); a6 += lo; a7 += hi;
    }
    if (j < end) {
        int i0 = col[j];
        uint4 u0 = *(const uint4*)(H + (size_t)i0 * HDIM + ch * 8);
        float lo, hi;
        unpack2(u0.x, lo, hi); a0 += lo; a1 += hi;
        unpack2(u0.y, lo, hi); a2 += lo; a3 += hi;
        unpack2(u0.z, lo, hi); a4 += lo; a5 += hi;
        unpack2(u0.w, lo, hi); a6 += lo; a7 += hi;
    }
    a0 += __shfl_xor(a0, 16); a0 += __shfl_xor(a0, 32);
    a1 += __shfl_xor(a1, 16); a1 += __shfl_xor(a1, 32);
    a2 += __shfl_xor(a2, 16); a2 += __shfl_xor(a2, 32);
    a3 += __shfl_xor(a3, 16); a3 += __shfl_xor(a3, 32);
    a4 += __shfl_xor(a4, 16); a4 += __shfl_xor(a4, 32);
    a5 += __shfl_xor(a5, 16); a5 += __shfl_xor(a5, 32);
    a6 += __shfl_xor(a6, 16); a6 += __shfl_xor(a6, 32);
    a7 += __shfl_xor(a7, 16); a7 += __shfl_xor(a7, 32);
    if (sub == 0) {
        float inv = 1.0f / (float)max(deg, 1);
        uint4 o;
        o.x = pack2(a0 * inv, a1 * inv);
        o.y = pack2(a2 * inv, a3 * inv);
        o.z = pack2(a4 * inv, a5 * inv);
        o.w = pack2(a6 * inv, a7 * inv);
        *(uint4*)(O + (size_t)node * HDIM + ch * 8) = o;
    }
}

// ---------------- classifier (bf16 tables): 16 lanes per edge ----------------
__global__ __launch_bounds__(256) void classify_bf16(const ushort* __restrict__ hp,
                                                     const ushort* __restrict__ hr,
                                                     const int* __restrict__ esrc,
                                                     const int* __restrict__ edst,
                                                     float* __restrict__ out, int n) {
    int t = blockIdx.x * blockDim.x + threadIdx.x;
    int edge = t >> 4;
    int ch = t & 15;
    if (edge >= n) return;
    int s = esrc[edge], d = edst[edge];
    uint4 ua = *(const uint4*)(hp + (size_t)s * HDIM + ch * 8);
    uint4 ub = *(const uint4*)(hr + (size_t)d * HDIM + ch * 8);
    float al, ah, bl, bh;
    float v = 0.f;
    unpack2(ua.x, al, ah); unpack2(ub.x, bl, bh); v += al * bl + ah * bh;
    unpack2(ua.y, al, ah); unpack2(ub.y, bl, bh); v += al * bl + ah * bh;
    unpack2(ua.z, al, ah); unpack2(ub.z, bl, bh); v += al * bl + ah * bh;
    unpack2(ua.w, al, ah); unpack2(ub.w, bl, bh); v += al * bl + ah * bh;
    v += __shfl_xor(v, 8);
    v += __shfl_xor(v, 4);
    v += __shfl_xor(v, 2);
    v += __shfl_xor(v, 1);
    if (ch == 0) out[edge] = v;
}

// ---------------- launch ----------------

extern "C" void kernel_launch(void* const* d_in, const int* in_sizes, int n_in,
                              void* d_out, int out_size, void* d_ws, size_t ws_size,
                              hipStream_t stream) {
    const float* x_pep   = (const float*)d_in[0];
    const float* x_prot  = (const float*)d_in[1];
    const int*   e_src   = (const int*)d_in[2];
    const int*   e_dst   = (const int*)d_in[3];
    const int*   el_src  = (const int*)d_in[4];
    const int*   el_dst  = (const int*)d_in[5];
    const float* W_pep   = (const float*)d_in[6];
    const float* b_pep   = (const float*)d_in[7];
    const float* W_prot  = (const float*)d_in[8];
    const float* b_prot  = (const float*)d_in[9];
    const float* Wl1_bind = (const float*)d_in[10];
    const float* Wr1_bind = (const float*)d_in[11];
    const float* Wl1_rev  = (const float*)d_in[12];
    const float* Wr1_rev  = (const float*)d_in[13];
    const float* Wl2_bind = (const float*)d_in[14];
    const float* Wr2_bind = (const float*)d_in[15];
    const float* Wl2_rev  = (const float*)d_in[16];
    const float* Wr2_rev  = (const float*)d_in[17];
    const float* b1_bind  = (const float*)d_in[18];
    const float* b1_rev   = (const float*)d_in[19];
    const float* b2_bind  = (const float*)d_in[20];
    const float* b2_rev   = (const float*)d_in[21];
    float* out = (float*)d_out;

    // workspace layout
    ushort* P0 = (ushort*)d_ws;
    ushort* P1 = P0 + (size_t)NP_PEP * HDIM;
    ushort* R0 = P1 + (size_t)NP_PEP * HDIM;
    ushort* R1 = R0 + (size_t)NP_PROT * HDIM;
    int* rowptr_pep  = (int*)(R1 + (size_t)NP_PROT * HDIM);
    int* rowptr_prot = rowptr_pep + NP_PEP + 1;
    int* col_pep     = rowptr_prot + NP_PROT + 1;
    int* col_prot    = col_pep + NE;
    uint* stagP      = (uint*)(col_prot + NE);
    uint* stagQ      = stagP + NE;
    int* Gq          = (int*)(stagQ + NE);       // [NBQ][NBLK]
    int* Oq          = Gq + NBQ * NBLK;
    int* Gp          = Oq + NBQ * NBLK;          // [NBP][NBLK]
    int* Op          = Gp + NBP * NBLK;
    int* Tq          = Op + NBP * NBLK;
    int* Tp          = Tq + NBQ;
    int* Bq          = Tp + NBP;                 // NBQ+1
    int* Bp          = Bq + NBQ + 1;             // NBP+1
    uintptr_t wraw   = (uintptr_t)(Bp + NBP + 1);
    ushort* Wst      = (ushort*)((wraw + 255) & ~(uintptr_t)255);  // 112 * 4096 ushorts

    const ushort* WstPep  = Wst;
    const ushort* WstProt = Wst + (size_t)40 * WST_TILE;
    const ushort* WstL1b  = Wst + (size_t)(80 + 0)  * WST_TILE;
    const ushort* WstR1b  = Wst + (size_t)(80 + 4)  * WST_TILE;
    const ushort* WstL1r  = Wst + (size_t)(80 + 8)  * WST_TILE;
    const ushort* WstR1r  = Wst + (size_t)(80 + 12) * WST_TILE;
    const ushort* WstL2b  = Wst + (size_t)(80 + 16) * WST_TILE;
    const ushort* WstR2b  = Wst + (size_t)(80 + 20) * WST_TILE;
    const ushort* WstL2r  = Wst + (size_t)(80 + 24) * WST_TILE;
    const ushort* WstR2r  = Wst + (size_t)(80 + 28) * WST_TILE;

    // ---- weight pre-bake (independent; must precede GEMMs) ----
    wprep<<<112, 256, 0, stream>>>(W_pep, W_prot,
                                   Wl1_bind, Wr1_bind, Wl1_rev, Wr1_rev,
                                   Wl2_bind, Wr2_bind, Wl2_rev, Wr2_rev, Wst);

    // ---- CSR build: 5 launches, all histograms/scans/cursors bucket-local in LDS ----
    bin_count<<<NBLK, 512, 0, stream>>>(e_src, e_dst, Gq, Gp);
    rel_offsets<<<NBQ + NBP, 512, 0, stream>>>(Gq, Oq, Tq, Gp, Op, Tp);
    base_scan<<<1, 512, 0, stream>>>(Tq, Bq, Tp, Bp);
    bin_scatter2<<<NBLK, 512, 0, stream>>>(e_src, e_dst, Oq, Bq, Op, Bp, stagQ, stagP);
    finalize_csr<<<NBQ + NBP, 256, 0, stream>>>(stagQ, Bq, rowptr_prot, col_prot,
                                                stagP, Bp, rowptr_pep, col_pep);

    // ---- input projections (merged: pep blocks first, then prot) ----
    gemm_proj2<<<PROJ_BLK_PEP + PROJ_BLK_PROT, 256, 0, stream>>>(
        x_pep, WstPep, b_pep, P0, NP_PEP, PROJ_BLK_PEP,
        x_prot, WstProt, b_prot, R0, NP_PROT);

    // ---- SAGE layer 1 (+relu) ----
    aggr2<<<AGG_BLK_PROT + AGG_BLK_PEP, 256, 0, stream>>>(
        P0, rowptr_prot, col_prot, R1, NP_PROT, AGG_BLK_PROT,
        R0, rowptr_pep, col_pep, P1, NP_PEP);
    lin2f<<<PROJ_BLK_PEP + PROJ_BLK_PROT, 256, 0, stream>>>(
        P1, WstL1r, P0, WstR1r, b1_rev, P1, NP_PEP, PROJ_BLK_PEP,
        R1, WstL1b, R0, WstR1b, b1_bind, R1, NP_PROT, 1);

    // ---- SAGE layer 2 ----
    aggr2<<<AGG_BLK_PROT + AGG_BLK_PEP, 256, 0, stream>>>(
        P1, rowptr_prot, col_prot, R0, NP_PROT, AGG_BLK_PROT,
        R1, rowptr_pep, col_pep, P0, NP_PEP);
    lin2f<<<PROJ_BLK_PEP + PROJ_BLK_PROT, 256, 0, stream>>>(
        P0, WstL2r, P1, WstR2r, b2_rev, P0, NP_PEP, PROJ_BLK_PEP,
        R0, WstL2b, R1, WstR2b, b2_bind, R0, NP_PROT, 0);

    // ---- classifier ----
    classify_bf16<<<(NEL * 16 + 255) / 256, 256, 0, stream>>>(P0, R0, el_src, el_dst, out, NEL);
}

// Round 2
// 636.315 us; speedup vs baseline: 1.2300x; 1.0448x over previous
//
#include <hip/hip_runtime.h>
#include <hip/hip_bf16.h>
#include <cstdint>

#define NP_PEP 50000
#define NP_PROT 8000
#define NE 1600000
#define NEL 200000
#define F_IN 1280
#define HDIM 128

// CSR binning constants
#define CHUNK 4096
#define NBLK 391            // ceil(NE/CHUNK)
#define NBQ 500             // prot buckets (16 nodes each, d>>4)
#define SHQ 4
#define NPBQ 16
#define NBP 391             // pep buckets (128 nodes each, s>>7)
#define SHP 7
#define NPBP 128

// grid split constants for merged kernels
#define PROJ_BLK_PEP 391    // ceil(50000/128)
#define PROJ_BLK_PROT 63    // ceil(8000/128)
#define PROJ_TOT (PROJ_BLK_PEP + PROJ_BLK_PROT)
#define AGG_BLK_PROT 2000   // ceil(8000/4)
#define AGG_BLK_PEP 12500   // ceil(50000/4)

typedef __attribute__((ext_vector_type(8))) short bfrag;   // 8 bf16 (4 VGPRs)
typedef __attribute__((ext_vector_type(4))) short bhalf4;  // 4 bf16 (8 B)
typedef __attribute__((ext_vector_type(4))) float f32x4;

__device__ __forceinline__ ushort f2bf(float x) {          // native RNE fp32->bf16
    __hip_bfloat16 h = __float2bfloat16(x);
    ushort u;
    __builtin_memcpy(&u, &h, 2);
    return u;
}
__device__ inline void unpack2(uint u, float& lo, float& hi) {
    union { uint u; float f; } a, b;
    a.u = u << 16; b.u = u & 0xffff0000u;
    lo = a.f; hi = b.f;
}
__device__ inline uint pack2(float a, float b) {
    return (uint)f2bf(a) | ((uint)f2bf(b) << 16);
}

// async 16B global -> LDS (wave-uniform base + lane*16; our layouts are linear in tid)
__device__ __forceinline__ void cp16_g2l(const void* g, void* l) {
    __builtin_amdgcn_global_load_lds(
        (const __attribute__((address_space(1))) void*)g,
        (__attribute__((address_space(3))) void*)l, 16, 0, 0);
}

// wave64 inclusive scan via shfl_up (exact int, no barriers)
__device__ __forceinline__ int wscan_incl(int x) {
#pragma unroll
    for (int d = 1; d < 64; d <<= 1) {
        int y = __shfl_up(x, d);
        if ((int)(threadIdx.x & 63) >= d) x += y;
    }
    return x;
}

// ---------------- weight pre-bake mapping helper ----------------
#define WST_TILE 4096

// ---------------- merged: wprep (112 blocks) + bin_count (391 blocks) ----------------
__global__ __launch_bounds__(512) void prep_count(const int* __restrict__ esrc,
                                                  const int* __restrict__ edst,
                                                  int* __restrict__ Gq,   // [NBQ][NBLK]
                                                  int* __restrict__ Gp,   // [NBP][NBLK]
                                                  const float* __restrict__ Wp,
                                                  const float* __restrict__ Wq,
                                                  const float* __restrict__ m0,
                                                  const float* __restrict__ m1,
                                                  const float* __restrict__ m2,
                                                  const float* __restrict__ m3,
                                                  const float* __restrict__ m4,
                                                  const float* __restrict__ m5,
                                                  const float* __restrict__ m6,
                                                  const float* __restrict__ m7,
                                                  ushort* __restrict__ wout) {
    int b = blockIdx.x;
    if (b >= NBLK) {
        // ---- wprep: fp32 W -> bf16 pre-swizzled B-fragment image (512 frags/tile) ----
        int bb = b - NBLK;
        const float* W; int kt; size_t base;
        if (bb < 40)      { W = Wp; kt = bb;       base = 0; }
        else if (bb < 80) { W = Wq; kt = bb - 40;  base = (size_t)40 * WST_TILE; }
        else {
            int mm = (bb - 80) >> 2; kt = (bb - 80) & 3;
            switch (mm) {
                case 0: W = m0; break; case 1: W = m1; break;
                case 2: W = m2; break; case 3: W = m3; break;
                case 4: W = m4; break; case 5: W = m5; break;
                case 6: W = m6; break; default: W = m7; break;
            }
            base = (size_t)(80 + 4 * mm) * WST_TILE;
        }
        int idx = threadIdx.x;                       // 0..511 covers full tile
        int n = ((idx >> 6) << 4) | (idx & 15);
        int h = (idx >> 4) & 3;
        const float* wp = W + (size_t)(kt * 32 + h * 8) * HDIM + n;
        bfrag p;
#pragma unroll
        for (int j = 0; j < 8; ++j) p[j] = (short)f2bf(wp[(size_t)j * HDIM]);
        *(bfrag*)&wout[base + (size_t)kt * WST_TILE + (size_t)idx * 8] = p;
        return;
    }
    // ---- bin_count ----
    __shared__ int hq[NBQ];
    __shared__ int hp[NBP];
    int t = threadIdx.x;
    if (t < NBQ) hq[t] = 0;
    if (t < NBP) hp[t] = 0;
    __syncthreads();
    int e0 = b * CHUNK, cnt = min(CHUNK, NE - e0);
#pragma unroll
    for (int r = 0; r < 8; ++r) {
        int i = t + r * 512;
        if (i < cnt) {
            atomicAdd(&hq[edst[e0 + i] >> SHQ], 1);
            atomicAdd(&hp[esrc[e0 + i] >> SHP], 1);
        }
    }
    __syncthreads();
    if (t < NBQ) Gq[t * NBLK + b] = hq[t];
    if (t < NBP) Gp[t * NBLK + b] = hp[t];
}

__global__ __launch_bounds__(512) void rel_offsets(const int* __restrict__ Gq,
                                                   int* __restrict__ Oq, int* __restrict__ Tq,
                                                   const int* __restrict__ Gp,
                                                   int* __restrict__ Op, int* __restrict__ Tp) {
    const int* G; int* O; int* T; int j;
    if (blockIdx.x < NBQ) { G = Gq; O = Oq; T = Tq; j = blockIdx.x; }
    else                  { G = Gp; O = Op; T = Tp; j = blockIdx.x - NBQ; }
    __shared__ int wsum[8];
    int t = threadIdx.x;
    int lane = t & 63, wid = t >> 6;
    int v = (t < NBLK) ? G[j * NBLK + t] : 0;
    int inc = wscan_incl(v);
    if (lane == 63) wsum[wid] = inc;
    __syncthreads();
    int add = 0;
#pragma unroll
    for (int w = 0; w < 7; ++w)
        if (w < wid) add += wsum[w];
    inc += add;
    if (t < NBLK) O[j * NBLK + t] = inc - v;
    if (t == 511) T[j] = inc;
}

__global__ __launch_bounds__(512) void base_scan(const int* __restrict__ Tq, int* __restrict__ Bq,
                                                 const int* __restrict__ Tp, int* __restrict__ Bp) {
    __shared__ int wsum[8];
    int t = threadIdx.x;
    int lane = t & 63, wid = t >> 6;
    int v = (t < NBQ) ? Tq[t] : 0;
    int inc = wscan_incl(v);
    if (lane == 63) wsum[wid] = inc;
    __syncthreads();
    int add = 0;
#pragma unroll
    for (int w = 0; w < 7; ++w)
        if (w < wid) add += wsum[w];
    inc += add;
    if (t < NBQ) Bq[t] = inc - v;
    if (t == 0) Bq[NBQ] = NE;
    __syncthreads();   // wsum reads done before rewrite
    int v2 = (t < NBP) ? Tp[t] : 0;
    int inc2 = wscan_incl(v2);
    if (lane == 63) wsum[wid] = inc2;
    __syncthreads();
    add = 0;
#pragma unroll
    for (int w = 0; w < 7; ++w)
        if (w < wid) add += wsum[w];
    inc2 += add;
    if (t < NBP) Bp[t] = inc2 - v2;
    if (t == 0) Bp[NBP] = NE;
}

// fused both-direction LDS counting sort of 4096-edge chunks; coalesced copy-out
__global__ __launch_bounds__(512) void bin_scatter2(const int* __restrict__ esrc,
                                                    const int* __restrict__ edst,
                                                    const int* __restrict__ Oq,
                                                    const int* __restrict__ Bq,
                                                    const int* __restrict__ Op,
                                                    const int* __restrict__ Bp,
                                                    uint* __restrict__ stagQ,
                                                    uint* __restrict__ stagP) {
    __shared__ int hist[512];
    __shared__ int start[512];
    __shared__ uint sorted[CHUNK];
    __shared__ int wsum[8];
    int b = blockIdx.x, t = threadIdx.x;
    int lane = t & 63, wid = t >> 6;
    int e0 = b * CHUNK, cnt = min(CHUNK, NE - e0);
    uint pk[8];
    bool val[8];
#pragma unroll
    for (int r = 0; r < 8; ++r) {
        int i = t + r * 512;
        val[r] = (i < cnt);
        if (val[r]) {
            int s = esrc[e0 + i], d = edst[e0 + i];
            pk[r] = ((uint)s << 13) | (uint)d;
        }
    }
    for (int dir = 0; dir < 2; ++dir) {
        const int* O = dir ? Op : Oq;
        const int* B = dir ? Bp : Bq;
        uint* stg = dir ? stagP : stagQ;
        int shf = dir ? SHP : SHQ;
        hist[t] = 0;
        __syncthreads();
        int bk[8];
#pragma unroll
        for (int r = 0; r < 8; ++r) {
            bk[r] = -1;
            if (val[r]) {
                int key = dir ? (int)(pk[r] >> 13) : (int)(pk[r] & 8191u);
                bk[r] = key >> shf;
                atomicAdd(&hist[bk[r]], 1);
            }
        }
        __syncthreads();
        int ownv = hist[t];
        int inc = wscan_incl(ownv);
        if (lane == 63) wsum[wid] = inc;
        __syncthreads();
        int add = 0;
#pragma unroll
        for (int w = 0; w < 7; ++w)
            if (w < wid) add += wsum[w];
        int excl = inc + add - ownv;
        start[t] = excl;
        hist[t] = excl;
        __syncthreads();
#pragma unroll
        for (int r = 0; r < 8; ++r)
            if (bk[r] >= 0) {
                int rank = atomicAdd(&hist[bk[r]], 1);
                sorted[rank] = pk[r];
            }
        __syncthreads();
#pragma unroll
        for (int r = 0; r < 8; ++r) {
            int i = t + r * 512;
            if (i < cnt) {
                uint v = sorted[i];
                int key = dir ? (int)(v >> 13) : (int)(v & 8191u);
                int bb = key >> shf;
                stg[B[bb] + O[bb * NBLK + b] + (i - start[bb])] = v;
            }
        }
        __syncthreads();
    }
}

// ------ merged: gemm_proj (454 blocks) + finalize_csr (891 blocks), both 256 thr ------
__global__ __launch_bounds__(256) void proj_fincsr(
    const float* __restrict__ Aa, const ushort* __restrict__ Wsta,
    const float* __restrict__ ba, ushort* __restrict__ Ca, int Ma,
    const float* __restrict__ Ab, const ushort* __restrict__ Wstb,
    const float* __restrict__ bb_, ushort* __restrict__ Cb, int Mb,
    const uint* __restrict__ stagQ, const int* __restrict__ Bq,
    int* __restrict__ rowptr_prot, int* __restrict__ col_prot,
    const uint* __restrict__ stagP, const int* __restrict__ Bp,
    int* __restrict__ rowptr_pep, int* __restrict__ col_pep) {
    __shared__ ushort Alds[4096];
    __shared__ ushort Blds[4096];
    __shared__ ushort Clds[128 * 136];
    int bx = blockIdx.x;
    int tid = threadIdx.x;
    if (bx < PROJ_TOT) {
        // ---------------- projection ----------------
        const float* A; const ushort* Wst; const float* bias; ushort* Cg; int M, blk;
        if (bx < PROJ_BLK_PEP) { A = Aa; Wst = Wsta; bias = ba; Cg = Ca; M = Ma; blk = bx; }
        else                   { A = Ab; Wst = Wstb; bias = bb_; Cg = Cb; M = Mb; blk = bx - PROJ_BLK_PEP; }
        int lane = tid & 63, w = tid >> 6, wm = w >> 1, wn = w & 1;
        int r0 = blk * 128;

        f32x4 acc[4][4];
#pragma unroll
        for (int i = 0; i < 4; ++i)
#pragma unroll
            for (int j = 0; j < 4; ++j) acc[i][j] = (f32x4){0.f, 0.f, 0.f, 0.f};

        for (int kt = 0; kt < F_IN / 32; ++kt) {
            int k0 = kt * 32;
            const ushort* wsrc = Wst + (size_t)kt * WST_TILE;
            cp16_g2l(wsrc + (size_t)tid * 8, &Blds[(size_t)tid * 8]);
            cp16_g2l(wsrc + 2048 + (size_t)tid * 8, &Blds[2048 + (size_t)tid * 8]);
#pragma unroll
            for (int i = 0; i < 4; ++i) {
                int idx = tid + 256 * i;
                int row = idx >> 3, q = idx & 7;
                int gr = min(r0 + row, M - 1);
                float4 v = *(const float4*)(A + (size_t)gr * F_IN + k0 + q * 4);
                bhalf4 p;
                p.x = (short)f2bf(v.x); p.y = (short)f2bf(v.y);
                p.z = (short)f2bf(v.z); p.w = (short)f2bf(v.w);
                int off = ((row >> 4) * 64 + ((q >> 1) << 4) + (row & 15)) * 8 + (q & 1) * 4;
                *(bhalf4*)&Alds[off] = p;
            }
            __syncthreads();
            const bfrag* Af = (const bfrag*)Alds;
            const bfrag* Bf = (const bfrag*)Blds;
            bfrag af[4], bf_[4];
#pragma unroll
            for (int i = 0; i < 4; ++i) af[i] = Af[(wm * 4 + i) * 64 + lane];
#pragma unroll
            for (int j = 0; j < 4; ++j) bf_[j] = Bf[(wn * 4 + j) * 64 + lane];
#pragma unroll
            for (int i = 0; i < 4; ++i)
#pragma unroll
                for (int j = 0; j < 4; ++j)
                    acc[i][j] = __builtin_amdgcn_mfma_f32_16x16x32_bf16(af[i], bf_[j], acc[i][j], 0, 0, 0);
            __syncthreads();
        }
#pragma unroll
        for (int j = 0; j < 4; ++j) {
            int colL = wn * 64 + j * 16 + (lane & 15);
            float bcol = bias[colL];
#pragma unroll
            for (int i = 0; i < 4; ++i) {
                int rbase = wm * 64 + i * 16 + ((lane >> 4) << 2);
                f32x4 v = acc[i][j];
                Clds[(rbase + 0) * 136 + colL] = f2bf(v.x + bcol);
                Clds[(rbase + 1) * 136 + colL] = f2bf(v.y + bcol);
                Clds[(rbase + 2) * 136 + colL] = f2bf(v.z + bcol);
                Clds[(rbase + 3) * 136 + colL] = f2bf(v.w + bcol);
            }
        }
        __syncthreads();
#pragma unroll
        for (int c = 0; c < 8; ++c) {
            int cidx = c * 256 + tid;
            int row = cidx >> 4, h = cidx & 15;
            int gr = r0 + row;
            if (gr < M)
                *(bfrag*)(Cg + (size_t)gr * HDIM + h * 8) = *(const bfrag*)&Clds[row * 136 + h * 8];
        }
        return;
    }
    // ---------------- finalize_csr (uses Alds as scratch) ----------------
    int fb = bx - PROJ_TOT;
    int* cnts = (int*)Alds;          // 128 ints
    int* cur  = cnts + 128;          // 128 ints
    int* wsf  = cur + 128;           // 1 int
    const uint* stg; const int* B; int* rowptr; int* col;
    int n, npb, j, use_dst;
    if (fb < NBQ) {
        stg = stagQ; B = Bq; rowptr = rowptr_prot; col = col_prot;
        n = NP_PROT; npb = NPBQ; j = fb; use_dst = 1;
    } else {
        stg = stagP; B = Bp; rowptr = rowptr_pep; col = col_pep;
        n = NP_PEP; npb = NPBP; j = fb - NBQ; use_dst = 0;
    }
    int t = tid;
    int first = j * npb;
    int nn = min(npb, n - first);
    if (t < 128) cnts[t] = 0;
    __syncthreads();
    int s0 = B[j], s1 = B[j + 1];
    for (int i = s0 + t; i < s1; i += 256) {
        uint v = stg[i];
        int key = use_dst ? (int)(v & 8191u) : (int)(v >> 13);
        atomicAdd(&cnts[key - first], 1);
    }
    __syncthreads();
    int v = (t < 128) ? cnts[t] : 0;
    int inc = wscan_incl(v);
    if (t == 63) wsf[0] = inc;
    __syncthreads();
    if (t >= 64 && t < 128) inc += wsf[0];
    if (t < 128) {
        int excl = inc - v;
        if (t < nn) rowptr[first + t] = s0 + excl;
        cur[t] = s0 + excl;
    }
    if (t == 0 && j == 0) rowptr[n] = NE;
    __syncthreads();
    for (int i = s0 + t; i < s1; i += 256) {
        uint v2 = stg[i];
        int key, pay;
        if (use_dst) { key = (int)(v2 & 8191u); pay = (int)(v2 >> 13); }
        else         { key = (int)(v2 >> 13);   pay = (int)(v2 & 8191u); }
        int pos = atomicAdd(&cur[key - first], 1);
        col[pos] = pay;
    }
}

// ---- merged fused linear (bf16): C = A1@W1 + A2@W2 + b (+relu), 2 jobs. C may alias A1.
__global__ __launch_bounds__(256) void lin2f(const ushort* A1a, const ushort* W1a,
                                             const ushort* A2a, const ushort* W2a,
                                             const float* __restrict__ ba,
                                             ushort* Ca, int Ma, int nblk_a,
                                             const ushort* A1b, const ushort* W1b,
                                             const ushort* A2b, const ushort* W2b,
                                             const float* __restrict__ bb,
                                             ushort* Cb, int Mb, int do_relu) {
    __shared__ ushort Alds[4096];
    __shared__ ushort Blds[4096];
    __shared__ ushort Clds[128 * 136];
    const ushort *A1, *A2, *W1, *W2; const float* bias; ushort* C; int M, blk;
    if ((int)blockIdx.x < nblk_a) {
        A1 = A1a; W1 = W1a; A2 = A2a; W2 = W2a; bias = ba; C = Ca; M = Ma; blk = blockIdx.x;
    } else {
        A1 = A1b; W1 = W1b; A2 = A2b; W2 = W2b; bias = bb; C = Cb; M = Mb; blk = blockIdx.x - nblk_a;
    }
    int tid = threadIdx.x;
    int lane = tid & 63, w = tid >> 6, wm = w >> 1, wn = w & 1;
    int r0 = blk * 128;

    int arow = ((tid >> 6) << 4) | (tid & 15);
    int ah = (tid >> 4) & 3;
    int gr1 = min(r0 + arow, M - 1);
    int gr2 = min(r0 + arow + 64, M - 1);

    f32x4 acc[4][4];
#pragma unroll
    for (int i = 0; i < 4; ++i)
#pragma unroll
        for (int j = 0; j < 4; ++j) acc[i][j] = (f32x4){0.f, 0.f, 0.f, 0.f};

    for (int kt = 0; kt < 8; ++kt) {
        const ushort* A = (kt < 4) ? A1 : A2;
        const ushort* Wt = (kt < 4) ? W1 : W2;
        int k0 = (kt & 3) * 32;
        cp16_g2l(A + (size_t)gr1 * HDIM + k0 + ah * 8, &Alds[(size_t)tid * 8]);
        cp16_g2l(A + (size_t)gr2 * HDIM + k0 + ah * 8, &Alds[(size_t)(tid + 256) * 8]);
        const ushort* wsrc = Wt + (size_t)(kt & 3) * WST_TILE;
        cp16_g2l(wsrc + (size_t)tid * 8, &Blds[(size_t)tid * 8]);
        cp16_g2l(wsrc + 2048 + (size_t)tid * 8, &Blds[2048 + (size_t)tid * 8]);
        __syncthreads();
        const bfrag* Af = (const bfrag*)Alds;
        const bfrag* Bf = (const bfrag*)Blds;
        bfrag af[4], bf_[4];
#pragma unroll
        for (int i = 0; i < 4; ++i) af[i] = Af[(wm * 4 + i) * 64 + lane];
#pragma unroll
        for (int j = 0; j < 4; ++j) bf_[j] = Bf[(wn * 4 + j) * 64 + lane];
#pragma unroll
        for (int i = 0; i < 4; ++i)
#pragma unroll
            for (int j = 0; j < 4; ++j)
                acc[i][j] = __builtin_amdgcn_mfma_f32_16x16x32_bf16(af[i], bf_[j], acc[i][j], 0, 0, 0);
        __syncthreads();
    }
#pragma unroll
    for (int j = 0; j < 4; ++j) {
        int colL = wn * 64 + j * 16 + (lane & 15);
        float bcol = bias[colL];
#pragma unroll
        for (int i = 0; i < 4; ++i) {
            int rbase = wm * 64 + i * 16 + ((lane >> 4) << 2);
            f32x4 v = acc[i][j];
            float o0 = v.x + bcol, o1 = v.y + bcol, o2 = v.z + bcol, o3 = v.w + bcol;
            if (do_relu) {
                o0 = fmaxf(o0, 0.f); o1 = fmaxf(o1, 0.f);
                o2 = fmaxf(o2, 0.f); o3 = fmaxf(o3, 0.f);
            }
            Clds[(rbase + 0) * 136 + colL] = f2bf(o0);
            Clds[(rbase + 1) * 136 + colL] = f2bf(o1);
            Clds[(rbase + 2) * 136 + colL] = f2bf(o2);
            Clds[(rbase + 3) * 136 + colL] = f2bf(o3);
        }
    }
    __syncthreads();
#pragma unroll
    for (int c = 0; c < 8; ++c) {
        int cidx = c * 256 + tid;
        int row = cidx >> 4, h = cidx & 15;
        int gr = r0 + row;
        if (gr < M)
            *(bfrag*)(C + (size_t)gr * HDIM + h * 8) = *(const bfrag*)&Clds[row * 136 + h * 8];
    }
}

// ------- merged mean aggregation (bf16 tables): one wave/node, 4-deep pipelined -------
__global__ __launch_bounds__(256) void aggr2(const ushort* __restrict__ Ha,
                                             const int* __restrict__ rpa,
                                             const int* __restrict__ cola,
                                             ushort* __restrict__ Oa, int Na, int nblk_a,
                                             const ushort* __restrict__ Hb,
                                             const int* __restrict__ rpb,
                                             const int* __restrict__ colb,
                                             ushort* __restrict__ Ob, int Nb) {
    const ushort* H; const int* rp; const int* col; ushort* O; int N, blk;
    if ((int)blockIdx.x < nblk_a) { H = Ha; rp = rpa; col = cola; O = Oa; N = Na; blk = blockIdx.x; }
    else                          { H = Hb; rp = rpb; col = colb; O = Ob; N = Nb; blk = blockIdx.x - nblk_a; }
    int node = blk * 4 + (threadIdx.x >> 6);
    if (node >= N) return;
    int lane = threadIdx.x & 63;
    int sub = lane >> 4;
    int ch = lane & 15;
    int beg = rp[node], end = rp[node + 1];
    int deg = end - beg;
    float a0 = 0, a1 = 0, a2 = 0, a3 = 0, a4 = 0, a5 = 0, a6 = 0, a7 = 0;
    int j = beg + sub;
    for (; j + 12 < end; j += 16) {
        int i0 = col[j], i1 = col[j + 4], i2 = col[j + 8], i3 = col[j + 12];
        uint4 u0 = *(const uint4*)(H + (size_t)i0 * HDIM + ch * 8);
        uint4 u1 = *(const uint4*)(H + (size_t)i1 * HDIM + ch * 8);
        uint4 u2 = *(const uint4*)(H + (size_t)i2 * HDIM + ch * 8);
        uint4 u3 = *(const uint4*)(H + (size_t)i3 * HDIM + ch * 8);
        float lo, hi;
        unpack2(u0.x, lo, hi); a0 += lo; a1 += hi;
        unpack2(u0.y, lo, hi); a2 += lo; a3 += hi;
        unpack2(u0.z, lo, hi); a4 += lo; a5 += hi;
        unpack2(u0.w, lo, hi); a6 += lo; a7 += hi;
        unpack2(u1.x, lo, hi); a0 += lo; a1 += hi;
        unpack2(u1.y, lo, hi); a2 += lo; a3 += hi;
        unpack2(u1.z, lo, hi); a4 += lo; a5 += hi;
        unpack2(u1.w, lo, hi); a6 += lo; a7 += hi;
        unpack2(u2.x, lo, hi); a0 += lo; a1 += hi;
        unpack2(u2.y, lo, hi); a2 += lo; a3 += hi;
        unpack2(u2.z, lo, hi); a4 += lo; a5 += hi;
        unpack2(u2.w, lo, hi); a6 += lo; a7 += hi;
        unpack2(u3.x, lo, hi); a0 += lo; a1 += hi;
        unpack2(u3.y, lo, hi); a2 += lo; a3 += hi;
        unpack2(u3.z, lo, hi); a4 += lo; a5 += hi;
        unpack2(u3.w, lo, hi); a6 += lo; a7 += hi;
    }
    for (; j + 4 < end; j += 8) {
        int i0 = col[j], i1 = col[j + 4];
        uint4 u0 = *(const uint4*)(H + (size_t)i0 * HDIM + ch * 8);
        uint4 u1 = *(const uint4*)(H + (size_t)i1 * HDIM + ch * 8);
        float lo, hi;
        unpack2(u0.x, lo, hi); a0 += lo; a1 += hi;
        unpack2(u0.y, lo, hi); a2 += lo; a3 += hi;
        unpack2(u0.z, lo, hi); a4 += lo; a5 += hi;
        unpack2(u0.w, lo, hi); a6 += lo; a7 += hi;
        unpack2(u1.x, lo, hi); a0 += lo; a1 += hi;
        unpack2(u1.y, lo, hi); a2 += lo; a3 += hi;
        unpack2(u1.z, lo, hi); a4 += lo; a5 += hi;
        unpack2(u1.w, lo, hi); a6 += lo; a7 += hi;
    }
    if (j < end) {
        int i0 = col[j];
        uint4 u0 = *(const uint4*)(H + (size_t)i0 * HDIM + ch * 8);
        float lo, hi;
        unpack2(u0.x, lo, hi); a0 += lo; a1 += hi;
        unpack2(u0.y, lo, hi); a2 += lo; a3 += hi;
        unpack2(u0.z, lo, hi); a4 += lo; a5 += hi;
        unpack2(u0.w, lo, hi); a6 += lo; a7 += hi;
    }
    a0 += __shfl_xor(a0, 16); a0 += __shfl_xor(a0, 32);
    a1 += __shfl_xor(a1, 16); a1 += __shfl_xor(a1, 32);
    a2 += __shfl_xor(a2, 16); a2 += __shfl_xor(a2, 32);
    a3 += __shfl_xor(a3, 16); a3 += __shfl_xor(a3, 32);
    a4 += __shfl_xor(a4, 16); a4 += __shfl_xor(a4, 32);
    a5 += __shfl_xor(a5, 16); a5 += __shfl_xor(a5, 32);
    a6 += __shfl_xor(a6, 16); a6 += __shfl_xor(a6, 32);
    a7 += __shfl_xor(a7, 16); a7 += __shfl_xor(a7, 32);
    if (sub == 0) {
        float inv = 1.0f / (float)max(deg, 1);
        uint4 o;
        o.x = pack2(a0 * inv, a1 * inv);
        o.y = pack2(a2 * inv, a3 * inv);
        o.z = pack2(a4 * inv, a5 * inv);
        o.w = pack2(a6 * inv, a7 * inv);
        *(uint4*)(O + (size_t)node * HDIM + ch * 8) = o;
    }
}

// ---------------- classifier (bf16 tables): 16 lanes per edge ----------------
__global__ __launch_bounds__(256) void classify_bf16(const ushort* __restrict__ hp,
                                                     const ushort* __restrict__ hr,
                                                     const int* __restrict__ esrc,
                                                     const int* __restrict__ edst,
                                                     float* __restrict__ out, int n) {
    int t = blockIdx.x * blockDim.x + threadIdx.x;
    int edge = t >> 4;
    int ch = t & 15;
    if (edge >= n) return;
    int s = esrc[edge], d = edst[edge];
    uint4 ua = *(const uint4*)(hp + (size_t)s * HDIM + ch * 8);
    uint4 ub = *(const uint4*)(hr + (size_t)d * HDIM + ch * 8);
    float al, ah, bl, bh;
    float v = 0.f;
    unpack2(ua.x, al, ah); unpack2(ub.x, bl, bh); v += al * bl + ah * bh;
    unpack2(ua.y, al, ah); unpack2(ub.y, bl, bh); v += al * bl + ah * bh;
    unpack2(ua.z, al, ah); unpack2(ub.z, bl, bh); v += al * bl + ah * bh;
    unpack2(ua.w, al, ah); unpack2(ub.w, bl, bh); v += al * bl + ah * bh;
    v += __shfl_xor(v, 8);
    v += __shfl_xor(v, 4);
    v += __shfl_xor(v, 2);
    v += __shfl_xor(v, 1);
    if (ch == 0) out[edge] = v;
}

// ---------------- launch ----------------

extern "C" void kernel_launch(void* const* d_in, const int* in_sizes, int n_in,
                              void* d_out, int out_size, void* d_ws, size_t ws_size,
                              hipStream_t stream) {
    const float* x_pep   = (const float*)d_in[0];
    const float* x_prot  = (const float*)d_in[1];
    const int*   e_src   = (const int*)d_in[2];
    const int*   e_dst   = (const int*)d_in[3];
    const int*   el_src  = (const int*)d_in[4];
    const int*   el_dst  = (const int*)d_in[5];
    const float* W_pep   = (const float*)d_in[6];
    const float* b_pep   = (const float*)d_in[7];
    const float* W_prot  = (const float*)d_in[8];
    const float* b_prot  = (const float*)d_in[9];
    const float* Wl1_bind = (const float*)d_in[10];
    const float* Wr1_bind = (const float*)d_in[11];
    const float* Wl1_rev  = (const float*)d_in[12];
    const float* Wr1_rev  = (const float*)d_in[13];
    const float* Wl2_bind = (const float*)d_in[14];
    const float* Wr2_bind = (const float*)d_in[15];
    const float* Wl2_rev  = (const float*)d_in[16];
    const float* Wr2_rev  = (const float*)d_in[17];
    const float* b1_bind  = (const float*)d_in[18];
    const float* b1_rev   = (const float*)d_in[19];
    const float* b2_bind  = (const float*)d_in[20];
    const float* b2_rev   = (const float*)d_in[21];
    float* out = (float*)d_out;

    // workspace layout
    ushort* P0 = (ushort*)d_ws;
    ushort* P1 = P0 + (size_t)NP_PEP * HDIM;
    ushort* R0 = P1 + (size_t)NP_PEP * HDIM;
    ushort* R1 = R0 + (size_t)NP_PROT * HDIM;
    int* rowptr_pep  = (int*)(R1 + (size_t)NP_PROT * HDIM);
    int* rowptr_prot = rowptr_pep + NP_PEP + 1;
    int* col_pep     = rowptr_prot + NP_PROT + 1;
    int* col_prot    = col_pep + NE;
    uint* stagP      = (uint*)(col_prot + NE);
    uint* stagQ      = stagP + NE;
    int* Gq          = (int*)(stagQ + NE);       // [NBQ][NBLK]
    int* Oq          = Gq + NBQ * NBLK;
    int* Gp          = Oq + NBQ * NBLK;          // [NBP][NBLK]
    int* Op          = Gp + NBP * NBLK;
    int* Tq          = Op + NBP * NBLK;
    int* Tp          = Tq + NBQ;
    int* Bq          = Tp + NBP;                 // NBQ+1
    int* Bp          = Bq + NBQ + 1;             // NBP+1
    uintptr_t wraw   = (uintptr_t)(Bp + NBP + 1);
    ushort* Wst      = (ushort*)((wraw + 255) & ~(uintptr_t)255);  // 112 * 4096 ushorts

    const ushort* WstPep  = Wst;
    const ushort* WstProt = Wst + (size_t)40 * WST_TILE;
    const ushort* WstL1b  = Wst + (size_t)(80 + 0)  * WST_TILE;
    const ushort* WstR1b  = Wst + (size_t)(80 + 4)  * WST_TILE;
    const ushort* WstL1r  = Wst + (size_t)(80 + 8)  * WST_TILE;
    const ushort* WstR1r  = Wst + (size_t)(80 + 12) * WST_TILE;
    const ushort* WstL2b  = Wst + (size_t)(80 + 16) * WST_TILE;
    const ushort* WstR2b  = Wst + (size_t)(80 + 20) * WST_TILE;
    const ushort* WstL2r  = Wst + (size_t)(80 + 24) * WST_TILE;
    const ushort* WstR2r  = Wst + (size_t)(80 + 28) * WST_TILE;

    // ---- CSR build + weight bake (merged stage 1), then scans, then scatter ----
    prep_count<<<NBLK + 112, 512, 0, stream>>>(e_src, e_dst, Gq, Gp,
                                               W_pep, W_prot,
                                               Wl1_bind, Wr1_bind, Wl1_rev, Wr1_rev,
                                               Wl2_bind, Wr2_bind, Wl2_rev, Wr2_rev, Wst);
    rel_offsets<<<NBQ + NBP, 512, 0, stream>>>(Gq, Oq, Tq, Gp, Op, Tp);
    base_scan<<<1, 512, 0, stream>>>(Tq, Bq, Tp, Bp);
    bin_scatter2<<<NBLK, 512, 0, stream>>>(e_src, e_dst, Oq, Bq, Op, Bp, stagQ, stagP);

    // ---- merged: input projections (454 blocks) + finalize CSR (891 blocks) ----
    proj_fincsr<<<PROJ_TOT + NBQ + NBP, 256, 0, stream>>>(
        x_pep, WstPep, b_pep, P0, NP_PEP,
        x_prot, WstProt, b_prot, R0, NP_PROT,
        stagQ, Bq, rowptr_prot, col_prot,
        stagP, Bp, rowptr_pep, col_pep);

    // ---- SAGE layer 1 (+relu) ----
    aggr2<<<AGG_BLK_PROT + AGG_BLK_PEP, 256, 0, stream>>>(
        P0, rowptr_prot, col_prot, R1, NP_PROT, AGG_BLK_PROT,
        R0, rowptr_pep, col_pep, P1, NP_PEP);
    lin2f<<<PROJ_BLK_PEP + PROJ_BLK_PROT, 256, 0, stream>>>(
        P1, WstL1r, P0, WstR1r, b1_rev, P1, NP_PEP, PROJ_BLK_PEP,
        R1, WstL1b, R0, WstR1b, b1_bind, R1, NP_PROT, 1);

    // ---- SAGE layer 2 ----
    aggr2<<<AGG_BLK_PROT + AGG_BLK_PEP, 256, 0, stream>>>(
        P1, rowptr_prot, col_prot, R0, NP_PROT, AGG_BLK_PROT,
        R1, rowptr_pep, col_pep, P0, NP_PEP);
    lin2f<<<PROJ_BLK_PEP + PROJ_BLK_PROT, 256, 0, stream>>>(
        P0, WstL2r, P1, WstR2r, b2_rev, P0, NP_PEP, PROJ_BLK_PEP,
        R0, WstL2b, R1, WstR2b, b2_bind, R0, NP_PROT, 0);

    // ---- classifier ----
    classify_bf16<<<(NEL * 16 + 255) / 256, 256, 0, stream>>>(P0, R0, el_src, el_dst, out, NEL);
}